// Round 6
// baseline (185.575 us; speedup 1.0000x reference)
//
#include <hip/hip_runtime.h>

#define NPTS 32768
#define DIM 256
#define KCODES 1024
#define NSPLIT 8                 // code-splits in the MFMA screen (128 codes/block)
#define BN 128                   // points per screen block
#define BKC 128                  // codes per screen block
#define LDSTR 40                 // screen LDS row stride in bf16 (80 B)
#define MARGIN 0.08f             // bf16 top-2 gap below which we np-emulate rescore
#define RG 8                     // rescore batch size (points per block pass)
#define RSPL 4                   // rescore code-splits (256 codes per split)
#define XDS (DIM + 8)            // xsT row stride in floats (16B-aligned)

typedef __attribute__((ext_vector_type(8))) short short8v;
typedef __attribute__((ext_vector_type(8))) unsigned short ushort8v;
typedef __attribute__((ext_vector_type(4))) float f32x4;

static __device__ __forceinline__ unsigned short f2bf(float f) {
    unsigned int u = __float_as_uint(f);
    unsigned int r = (u + 0x7fffu + ((u >> 16) & 1u)) >> 16;   // RNE
    return (unsigned short)r;
}

// ---------------- phase -1a: f32 -> bf16 conversion of X and E ----------------
__global__ void convert_kernel(const float* __restrict__ X, const float* __restrict__ E,
                               unsigned short* __restrict__ Xb, unsigned short* __restrict__ Eb) {
    int i = blockIdx.x * 256 + threadIdx.x;
    size_t e8 = (size_t)i * 8;
    const float* src; unsigned short* dst; size_t off;
    if (e8 < (size_t)NPTS * DIM) { src = X; dst = Xb; off = e8; }
    else { src = E; dst = Eb; off = e8 - (size_t)NPTS * DIM; }
    float4 f0 = *(const float4*)(src + off);
    float4 f1 = *(const float4*)(src + off + 4);
    ushort8v v;
    v[0] = f2bf(f0.x); v[1] = f2bf(f0.y); v[2] = f2bf(f0.z); v[3] = f2bf(f0.w);
    v[4] = f2bf(f1.x); v[5] = f2bf(f1.y); v[6] = f2bf(f1.z); v[7] = f2bf(f1.w);
    *(ushort8v*)(dst + off) = v;
}

// ---------------- phase -1b: E transpose Et[d][c] = E[c][d] (exact copy) ----------------
__global__ void etrans_kernel(const float* __restrict__ E, float* __restrict__ Et) {
    __shared__ float tile[32][33];
    const int tx = threadIdx.x & 31;
    const int ty = threadIdx.x >> 5;
    const int c0 = blockIdx.x * 32;
    const int d0 = blockIdx.y * 32;
#pragma unroll
    for (int r = 0; r < 4; ++r)
        tile[ty + r * 8][tx] = E[(size_t)(c0 + ty + r * 8) * DIM + d0 + tx];
    __syncthreads();
#pragma unroll
    for (int r = 0; r < 4; ++r)
        Et[(size_t)(d0 + ty + r * 8) * KCODES + c0 + tx] = tile[tx][ty + r * 8];
}

// ---------------- phase 0a: fast fp32 embedding norms (screening) ----------------
__global__ void enorm_kernel(const float* __restrict__ E, float* __restrict__ enorm,
                             int* __restrict__ counter) {
    if (blockIdx.x == 0 && threadIdx.x == 0) counter[0] = 0;
    int wave = threadIdx.x >> 6;
    int lane = threadIdx.x & 63;
    int k = blockIdx.x * 4 + wave;
    float4 v = *(const float4*)(E + (size_t)k * DIM + lane * 4);
    float s = v.x * v.x + v.y * v.y + v.z * v.z + v.w * v.w;
#pragma unroll
    for (int m = 32; m >= 1; m >>= 1) s += __shfl_xor(s, m);
    if (lane == 0) enorm[k] = s;
}

// ---------------- phase 0b: numpy-faithful ||e||^2 (pairwise emulation) ----------------
__global__ void enormnp_kernel(const float* __restrict__ E, float* __restrict__ Cnp) {
#pragma clang fp contract(off)
    int k = blockIdx.x * 256 + threadIdx.x;
    const float* e = E + (size_t)k * DIM;
    float half[2];
    for (int h = 0; h < 2; ++h) {
        const float* b = e + h * 128;
        float s[8];
#pragma unroll
        for (int j = 0; j < 8; ++j) { float v = b[j]; s[j] = v * v; }
        for (int i = 8; i < 128; i += 8) {
#pragma unroll
            for (int j = 0; j < 8; ++j) { float v = b[i + j]; s[j] += v * v; }
        }
        half[h] = ((s[0] + s[1]) + (s[2] + s[3])) + ((s[4] + s[5]) + (s[6] + s[7]));
    }
    Cnp[k] = half[0] + half[1];
}

// ---------------- phase 1: bf16-MFMA distance screen + per-split top-2 ----------------
__global__ __launch_bounds__(256, 3) void dist_kernel(
        const unsigned short* __restrict__ Xb, const unsigned short* __restrict__ Eb,
        const float* __restrict__ enorm,
        float* __restrict__ ws_minv, float* __restrict__ ws_min2,
        int* __restrict__ ws_midx) {
    __shared__ unsigned short xs[BN * LDSTR];
    __shared__ unsigned short es[BKC * LDSTR];

    const int tid = threadIdx.x;
    const int lane = tid & 63;
    const int wave = tid >> 6;
    const int wr = wave >> 1, wc = wave & 1;
    const int lg = lane >> 4, lc = lane & 15;
    const int pbase = blockIdx.x * BN;
    const int cbase = blockIdx.y * BKC;

    f32x4 acc[4][4];
#pragma unroll
    for (int i = 0; i < 4; ++i)
#pragma unroll
        for (int j = 0; j < 4; ++j) acc[i][j] = (f32x4){0.f, 0.f, 0.f, 0.f};

    const int srow = tid >> 1, shalf = tid & 1;
    for (int ks = 0; ks < DIM / 32; ++ks) {
        const int k0 = ks * 32;
        __syncthreads();
        {
            const unsigned short* sx = Xb + (size_t)(pbase + srow) * DIM + k0 + shalf * 16;
            ushort8v x0 = *(const ushort8v*)sx;
            ushort8v x1 = *(const ushort8v*)(sx + 8);
            *(ushort8v*)&xs[srow * LDSTR + shalf * 16] = x0;
            *(ushort8v*)&xs[srow * LDSTR + shalf * 16 + 8] = x1;
            const unsigned short* se = Eb + (size_t)(cbase + srow) * DIM + k0 + shalf * 16;
            ushort8v e0 = *(const ushort8v*)se;
            ushort8v e1 = *(const ushort8v*)(se + 8);
            *(ushort8v*)&es[srow * LDSTR + shalf * 16] = e0;
            *(ushort8v*)&es[srow * LDSTR + shalf * 16 + 8] = e1;
        }
        __syncthreads();
        short8v a[4], b[4];
#pragma unroll
        for (int f = 0; f < 4; ++f)
            a[f] = *(const short8v*)&xs[(wr * 64 + f * 16 + lc) * LDSTR + lg * 8];
#pragma unroll
        for (int f = 0; f < 4; ++f)
            b[f] = *(const short8v*)&es[(wc * 64 + f * 16 + lc) * LDSTR + lg * 8];
#pragma unroll
        for (int i = 0; i < 4; ++i)
#pragma unroll
            for (int j = 0; j < 4; ++j)
                acc[i][j] = __builtin_amdgcn_mfma_f32_16x16x32_bf16(a[i], b[j], acc[i][j], 0, 0, 0);
    }

    float bv1[4][4], bv2[4][4]; int bi1[4][4];
#pragma unroll
    for (int i = 0; i < 4; ++i)
#pragma unroll
        for (int r = 0; r < 4; ++r) { bv1[i][r] = 3.4e38f; bv2[i][r] = 3.4e38f; bi1[i][r] = 0; }

#pragma unroll
    for (int j = 0; j < 4; ++j) {
        int cg = cbase + wc * 64 + j * 16 + lc;
        float en = enorm[cg];
#pragma unroll
        for (int i = 0; i < 4; ++i)
#pragma unroll
            for (int r = 0; r < 4; ++r) {
                float d = en - 2.f * acc[i][j][r];
                if (d < bv1[i][r]) { bv2[i][r] = bv1[i][r]; bv1[i][r] = d; bi1[i][r] = cg; }
                else if (d < bv2[i][r]) bv2[i][r] = d;
            }
    }
#pragma unroll
    for (int m = 1; m < 16; m <<= 1) {
#pragma unroll
        for (int i = 0; i < 4; ++i)
#pragma unroll
            for (int r = 0; r < 4; ++r) {
                float o1 = __shfl_xor(bv1[i][r], m);
                float o2 = __shfl_xor(bv2[i][r], m);
                int oi = __shfl_xor(bi1[i][r], m);
                if (o1 < bv1[i][r] || (o1 == bv1[i][r] && oi < bi1[i][r])) {
                    bv2[i][r] = fminf(bv1[i][r], o2);
                    bv1[i][r] = o1; bi1[i][r] = oi;
                } else {
                    bv2[i][r] = fminf(bv2[i][r], o1);
                }
            }
    }

    __syncthreads();
    float* sv1 = (float*)xs;
    float* sv2 = sv1 + 256;
    int* si1 = (int*)(sv1 + 512);
    if (lc == 0) {
#pragma unroll
        for (int i = 0; i < 4; ++i)
#pragma unroll
            for (int r = 0; r < 4; ++r) {
                int ploc = wr * 64 + i * 16 + lg * 4 + r;
                sv1[wc * 128 + ploc] = bv1[i][r];
                sv2[wc * 128 + ploc] = bv2[i][r];
                si1[wc * 128 + ploc] = bi1[i][r];
            }
    }
    __syncthreads();
    if (tid < 128) {
        float v1 = sv1[tid], v2 = sv2[tid]; int i1 = si1[tid];
        float o1 = sv1[128 + tid], o2 = sv2[128 + tid]; int oi = si1[128 + tid];
        if (o1 < v1 || (o1 == v1 && oi < i1)) {
            v2 = fminf(v1, o2); v1 = o1; i1 = oi;
        } else {
            v2 = fminf(v2, o1);
        }
        size_t p = pbase + tid;
        ws_minv[p * NSPLIT + blockIdx.y] = v1;
        ws_min2[p * NSPLIT + blockIdx.y] = v2;
        ws_midx[p * NSPLIT + blockIdx.y] = i1;
    }
}

// ---------------- phase 2: combine splits, flag ambiguous points ----------------
__global__ void resolve_kernel(const float* __restrict__ ws_minv, const float* __restrict__ ws_min2,
                               const int* __restrict__ ws_midx,
                               int* __restrict__ final_idx, int* __restrict__ list,
                               int* __restrict__ counter) {
    const int p = blockIdx.x * 256 + threadIdx.x;
    float v1 = ws_minv[(size_t)p * NSPLIT];
    float v2 = ws_min2[(size_t)p * NSPLIT];
    int i1 = ws_midx[(size_t)p * NSPLIT];
#pragma unroll
    for (int s = 1; s < NSPLIT; ++s) {
        float b1 = ws_minv[(size_t)p * NSPLIT + s];
        float b2 = ws_min2[(size_t)p * NSPLIT + s];
        int bi = ws_midx[(size_t)p * NSPLIT + s];
        if (b1 < v1 || (b1 == v1 && bi < i1)) {
            v2 = fminf(v1, b2); v1 = b1; i1 = bi;
        } else {
            v2 = fminf(v2, b1);
        }
    }
    final_idx[p] = i1;
    if (v2 - v1 <= MARGIN) {
        int slot = atomicAdd(counter, 1);
        list[slot] = p;
    }
}

// ---------------- phase 3: np-fp32-emulating rescore, code-split x4 ----------------
// Per (point,code): d = fl32(fl32(A - 2*B) + C); B = sequential ascending-d fp32
// fma chain; A = np-pairwise sum x^2; C = Cnp. Bit-identical arithmetic to the
// round-3..5 passing versions — blocks now also split the 1024 codes 4-ways
// (grid.y), 1 code/thread, partial argmin per split -> combine_kernel.
__global__ __launch_bounds__(256) void rescore_np_kernel(
        const float* __restrict__ X, const float* __restrict__ Et,
        const float* __restrict__ Cnp,
        const int* __restrict__ list, const int* __restrict__ counter,
        float* __restrict__ pval, int* __restrict__ pidx) {
#pragma clang fp contract(off)
    const int tid = threadIdx.x;
    const int lane = tid & 63;
    const int wave = tid >> 6;
    const int split = blockIdx.y;
    const int c = split * 256 + tid;          // this thread's code
    const int cnt = counter[0];
    __shared__ float xsT[RG][XDS];            // x rows, float4-readable
    __shared__ float Ash[RG];
    __shared__ float sA[RG][2][8];
    __shared__ int plist[RG];
    __shared__ float wv[4][RG];
    __shared__ int wi[4][RG];

    for (int base = blockIdx.x * RG; base < cnt; base += gridDim.x * RG) {
        const int gs = min(RG, cnt - base);
        __syncthreads();
        if (tid < RG) plist[tid] = list[base + (tid < gs ? tid : gs - 1)];
        __syncthreads();
#pragma unroll
        for (int g = 0; g < RG; ++g)
            xsT[g][tid] = X[(size_t)plist[g] * DIM + tid];
        __syncthreads();
        // A: np-pairwise sum of x^2 — thread (g, j) computes accumulator j per half
        if (tid < RG * 8) {
            const int g = tid >> 3, j = tid & 7;
#pragma unroll
            for (int h = 0; h < 2; ++h) {
                float v = xsT[g][h * 128 + j];
                float s = v * v;
                for (int i = 8; i < 128; i += 8) {
                    float w = xsT[g][h * 128 + i + j];
                    s += w * w;
                }
                sA[g][h][j] = s;
            }
        }
        __syncthreads();
        if (tid < RG) {
            float h0 = ((sA[tid][0][0] + sA[tid][0][1]) + (sA[tid][0][2] + sA[tid][0][3]))
                     + ((sA[tid][0][4] + sA[tid][0][5]) + (sA[tid][0][6] + sA[tid][0][7]));
            float h1 = ((sA[tid][1][0] + sA[tid][1][1]) + (sA[tid][1][2] + sA[tid][1][3]))
                     + ((sA[tid][1][4] + sA[tid][1][5]) + (sA[tid][1][6] + sA[tid][1][7]));
            Ash[tid] = h0 + h1;
        }
        __syncthreads();

        // B: 1 code/thread, RG points; ascending-d chain; Et loads coalesced dwords
        float acc[RG];
#pragma unroll
        for (int g = 0; g < RG; ++g) acc[g] = 0.f;
        for (int d4 = 0; d4 < DIM; d4 += 4) {
            float e0 = Et[(size_t)(d4 + 0) * KCODES + c];
            float e1 = Et[(size_t)(d4 + 1) * KCODES + c];
            float e2 = Et[(size_t)(d4 + 2) * KCODES + c];
            float e3 = Et[(size_t)(d4 + 3) * KCODES + c];
#pragma unroll
            for (int g = 0; g < RG; ++g) {
                float4 xv = *(const float4*)&xsT[g][d4];
                acc[g] = __builtin_fmaf(xv.x, e0, acc[g]);
                acc[g] = __builtin_fmaf(xv.y, e1, acc[g]);
                acc[g] = __builtin_fmaf(xv.z, e2, acc[g]);
                acc[g] = __builtin_fmaf(xv.w, e3, acc[g]);
            }
        }
        float cn = Cnp[c];
        float bv[RG]; int bi[RG];
#pragma unroll
        for (int g = 0; g < RG; ++g) {
            float t1 = Ash[g] - 2.0f * acc[g];
            bv[g] = t1 + cn;
            bi[g] = c;
        }
        // wave argmin (codes ascend with tid), then cross-wave, then write partial
#pragma unroll
        for (int m = 1; m < 64; m <<= 1) {
#pragma unroll
            for (int g = 0; g < RG; ++g) {
                float ov = __shfl_xor(bv[g], m);
                int oi = __shfl_xor(bi[g], m);
                if (ov < bv[g] || (ov == bv[g] && oi < bi[g])) { bv[g] = ov; bi[g] = oi; }
            }
        }
        if (lane == 0) {
#pragma unroll
            for (int g = 0; g < RG; ++g) { wv[wave][g] = bv[g]; wi[wave][g] = bi[g]; }
        }
        __syncthreads();
        if (tid < gs) {
            float v = wv[0][tid]; int i = wi[0][tid];
#pragma unroll
            for (int w = 1; w < 4; ++w) {
                float ov = wv[w][tid]; int oi = wi[w][tid];
                if (ov < v || (ov == v && oi < i)) { v = ov; i = oi; }
            }
            pval[(size_t)(base + tid) * RSPL + split] = v;
            pidx[(size_t)(base + tid) * RSPL + split] = i;
        }
    }
}

// ---------------- phase 3b: combine rescore code-splits ----------------
__global__ void combine_kernel(const int* __restrict__ list, const int* __restrict__ counter,
                               const float* __restrict__ pval, const int* __restrict__ pidx,
                               int* __restrict__ final_idx) {
    const int li = blockIdx.x * 256 + threadIdx.x;
    if (li >= counter[0]) return;
    float v = pval[(size_t)li * RSPL];
    int i = pidx[(size_t)li * RSPL];
#pragma unroll
    for (int s = 1; s < RSPL; ++s) {
        float ov = pval[(size_t)li * RSPL + s];
        int oi = pidx[(size_t)li * RSPL + s];
        if (ov < v || (ov == v && oi < i)) { v = ov; i = oi; }
    }
    final_idx[list[li]] = i;
}

// ---------------- phase 4: gather, write quantized/indices, loss partials ----------------
__global__ void gather_kernel(const float* __restrict__ X, const float* __restrict__ E,
                              const int* __restrict__ final_idx,
                              float* __restrict__ out_q, float* __restrict__ out_idx,
                              float* __restrict__ ws_part) {
    const int tid = threadIdx.x;
    const int p = blockIdx.x * 16 + (tid >> 4);
    const int c = tid & 15;
    const int bi = final_idx[p];

    float ls = 0.f;
#pragma unroll
    for (int k = 0; k < 4; ++k) {
        int d4 = c + k * 16;
        float4 e4 = *(const float4*)(E + (size_t)bi * DIM + d4 * 4);
        float4 x4 = *(const float4*)(X + (size_t)p * DIM + d4 * 4);
        *(float4*)(out_q + (size_t)p * DIM + d4 * 4) = e4;
        float dx = e4.x - x4.x, dy = e4.y - x4.y, dz = e4.z - x4.z, dw = e4.w - x4.w;
        ls += dx * dx + dy * dy + dz * dz + dw * dw;
    }
    if (c == 0) out_idx[p] = (float)bi;

    __shared__ float red[256];
    red[tid] = ls;
    __syncthreads();
#pragma unroll
    for (int s = 128; s > 0; s >>= 1) {
        if (tid < s) red[tid] += red[tid + s];
        __syncthreads();
    }
    if (tid == 0) ws_part[blockIdx.x] = red[0];
}

// ---------------- phase 5: final loss reduce ----------------
__global__ void loss_kernel(const float* __restrict__ ws_part, float* __restrict__ out_loss) {
    const int tid = threadIdx.x;
    float s = 0.f;
    for (int i = tid; i < NPTS / 16; i += 256) s += ws_part[i];
    __shared__ float red[256];
    red[tid] = s;
    __syncthreads();
#pragma unroll
    for (int t = 128; t > 0; t >>= 1) {
        if (tid < t) red[tid] += red[tid + t];
        __syncthreads();
    }
    if (tid == 0)
        out_loss[0] = (1.f + 0.25f) * red[0] / (float)((size_t)NPTS * DIM);
}

extern "C" void kernel_launch(void* const* d_in, const int* in_sizes, int n_in,
                              void* d_out, int out_size, void* d_ws, size_t ws_size,
                              hipStream_t stream) {
    const float* X = (const float*)d_in[0];   // [32768, 256]
    const float* E = (const float*)d_in[1];   // [1024, 256]
    float* out = (float*)d_out;
    float* out_q = out;                                 // 8388608 floats
    float* out_loss = out + (size_t)NPTS * DIM;         // 1 float
    float* out_idx = out + (size_t)NPTS * DIM + 1;      // 32768 floats

    // staging inside out_q (rewritten by gather afterward):
    // Xb (16.8MB) + Eb (0.5MB) + Et (1MB) + pval/pidx (1MB) = 19.3MB < 33.5MB
    unsigned short* Xb = (unsigned short*)d_out;
    unsigned short* Eb = Xb + (size_t)NPTS * DIM;
    float* Et = (float*)(Eb + (size_t)KCODES * DIM);
    float* pval = Et + (size_t)DIM * KCODES;            // NPTS*4 floats
    int* pidx = (int*)(pval + (size_t)NPTS * RSPL);     // NPTS*4 ints

    float* ws = (float*)d_ws;
    float* enorm = ws;                                  // 1024
    float* Cnp = enorm + KCODES;                        // 1024
    float* ws_minv = Cnp + KCODES;                      // 32768*8
    float* ws_min2 = ws_minv + (size_t)NPTS * NSPLIT;   // 32768*8
    int* ws_midx = (int*)(ws_min2 + (size_t)NPTS * NSPLIT);  // 32768*8 ints
    int* final_idx = ws_midx + (size_t)NPTS * NSPLIT;   // 32768 ints
    int* counter = final_idx + NPTS;                    // 1 int (+63 pad)
    int* list = counter + 64;                           // 32768 ints
    float* ws_part = (float*)(list + NPTS);             // 2048 floats

    convert_kernel<<<(NPTS + KCODES) * DIM / 8 / 256, 256, 0, stream>>>(X, E, Xb, Eb);
    etrans_kernel<<<dim3(KCODES / 32, DIM / 32), 256, 0, stream>>>(E, Et);
    enorm_kernel<<<KCODES / 4, 256, 0, stream>>>(E, enorm, counter);
    enormnp_kernel<<<KCODES / 256, 256, 0, stream>>>(E, Cnp);
    dist_kernel<<<dim3(NPTS / BN, NSPLIT), 256, 0, stream>>>(Xb, Eb, enorm,
                                                             ws_minv, ws_min2, ws_midx);
    resolve_kernel<<<NPTS / 256, 256, 0, stream>>>(ws_minv, ws_min2, ws_midx,
                                                   final_idx, list, counter);
    rescore_np_kernel<<<dim3(256, RSPL), 256, 0, stream>>>(X, Et, Cnp, list, counter,
                                                           pval, pidx);
    combine_kernel<<<NPTS / 256, 256, 0, stream>>>(list, counter, pval, pidx, final_idx);
    gather_kernel<<<NPTS / 16, 256, 0, stream>>>(X, E, final_idx, out_q, out_idx, ws_part);
    loss_kernel<<<1, 256, 0, stream>>>(ws_part, out_loss);
}

// Round 7
// 133.372 us; speedup vs baseline: 1.3914x; 1.3914x over previous
//
#include <hip/hip_runtime.h>

#define NPTS 32768
#define DIM 256
#define KCODES 1024
#define NSPLIT 8                 // code-splits in the MFMA screen (128 codes/block)
#define BN 128                   // points per screen block
#define BKC 128                  // codes per screen block
#define LDSTR 40                 // screen LDS row stride in bf16 (80 B)
#define MARGIN 0.08f             // bf16 top-2 gap band: flag + candidate threshold

typedef __attribute__((ext_vector_type(8))) short short8v;
typedef __attribute__((ext_vector_type(8))) unsigned short ushort8v;
typedef __attribute__((ext_vector_type(4))) float f32x4;

static __device__ __forceinline__ unsigned short f2bf(float f) {
    unsigned int u = __float_as_uint(f);
    unsigned int r = (u + 0x7fffu + ((u >> 16) & 1u)) >> 16;   // RNE
    return (unsigned short)r;
}

// ---------------- phase -1: f32 -> bf16 conversion of X and E ----------------
__global__ void convert_kernel(const float* __restrict__ X, const float* __restrict__ E,
                               unsigned short* __restrict__ Xb, unsigned short* __restrict__ Eb) {
    int i = blockIdx.x * 256 + threadIdx.x;
    size_t e8 = (size_t)i * 8;
    const float* src; unsigned short* dst; size_t off;
    if (e8 < (size_t)NPTS * DIM) { src = X; dst = Xb; off = e8; }
    else { src = E; dst = Eb; off = e8 - (size_t)NPTS * DIM; }
    float4 f0 = *(const float4*)(src + off);
    float4 f1 = *(const float4*)(src + off + 4);
    ushort8v v;
    v[0] = f2bf(f0.x); v[1] = f2bf(f0.y); v[2] = f2bf(f0.z); v[3] = f2bf(f0.w);
    v[4] = f2bf(f1.x); v[5] = f2bf(f1.y); v[6] = f2bf(f1.z); v[7] = f2bf(f1.w);
    *(ushort8v*)(dst + off) = v;
}

// ---------------- phase 0a: fast fp32 embedding norms (screening) ----------------
__global__ void enorm_kernel(const float* __restrict__ E, float* __restrict__ enorm,
                             int* __restrict__ counter) {
    if (blockIdx.x == 0 && threadIdx.x == 0) counter[0] = 0;
    int wave = threadIdx.x >> 6;
    int lane = threadIdx.x & 63;
    int k = blockIdx.x * 4 + wave;
    float4 v = *(const float4*)(E + (size_t)k * DIM + lane * 4);
    float s = v.x * v.x + v.y * v.y + v.z * v.z + v.w * v.w;
#pragma unroll
    for (int m = 32; m >= 1; m >>= 1) s += __shfl_xor(s, m);
    if (lane == 0) enorm[k] = s;
}

// ---------------- phase 0b: numpy-faithful ||e||^2 (pairwise emulation) ----------------
__global__ void enormnp_kernel(const float* __restrict__ E, float* __restrict__ Cnp) {
#pragma clang fp contract(off)
    int k = blockIdx.x * 256 + threadIdx.x;
    const float* e = E + (size_t)k * DIM;
    float half[2];
    for (int h = 0; h < 2; ++h) {
        const float* b = e + h * 128;
        float s[8];
#pragma unroll
        for (int j = 0; j < 8; ++j) { float v = b[j]; s[j] = v * v; }
        for (int i = 8; i < 128; i += 8) {
#pragma unroll
            for (int j = 0; j < 8; ++j) { float v = b[i + j]; s[j] += v * v; }
        }
        half[h] = ((s[0] + s[1]) + (s[2] + s[3])) + ((s[4] + s[5]) + (s[6] + s[7]));
    }
    Cnp[k] = half[0] + half[1];
}

// ---------------- phase 1: bf16-MFMA screen: top-2 + candidate bitmaps ----------------
// grid (NPTS/128, 8 splits), 256 threads = 4 waves (2x2 of 64x64 MFMA tiles).
// Epilogue additionally emits, per (point, split), a 128-bit bitmap of codes
// with dist <= split_min + MARGIN (superset of the global-min band).
__global__ __launch_bounds__(256, 3) void dist_kernel(
        const unsigned short* __restrict__ Xb, const unsigned short* __restrict__ Eb,
        const float* __restrict__ enorm,
        float* __restrict__ ws_minv, float* __restrict__ ws_min2,
        int* __restrict__ ws_midx, unsigned int* __restrict__ cand) {
    __shared__ unsigned short xs[BN * LDSTR];
    __shared__ unsigned short es[BKC * LDSTR];

    const int tid = threadIdx.x;
    const int lane = tid & 63;
    const int wave = tid >> 6;
    const int wr = wave >> 1, wc = wave & 1;
    const int lg = lane >> 4, lc = lane & 15;
    const int pbase = blockIdx.x * BN;
    const int split = blockIdx.y;
    const int cbase = split * BKC;

    f32x4 acc[4][4];
#pragma unroll
    for (int i = 0; i < 4; ++i)
#pragma unroll
        for (int j = 0; j < 4; ++j) acc[i][j] = (f32x4){0.f, 0.f, 0.f, 0.f};

    const int srow = tid >> 1, shalf = tid & 1;
    for (int ks = 0; ks < DIM / 32; ++ks) {
        const int k0 = ks * 32;
        __syncthreads();
        {
            const unsigned short* sx = Xb + (size_t)(pbase + srow) * DIM + k0 + shalf * 16;
            ushort8v x0 = *(const ushort8v*)sx;
            ushort8v x1 = *(const ushort8v*)(sx + 8);
            *(ushort8v*)&xs[srow * LDSTR + shalf * 16] = x0;
            *(ushort8v*)&xs[srow * LDSTR + shalf * 16 + 8] = x1;
            const unsigned short* se = Eb + (size_t)(cbase + srow) * DIM + k0 + shalf * 16;
            ushort8v e0 = *(const ushort8v*)se;
            ushort8v e1 = *(const ushort8v*)(se + 8);
            *(ushort8v*)&es[srow * LDSTR + shalf * 16] = e0;
            *(ushort8v*)&es[srow * LDSTR + shalf * 16 + 8] = e1;
        }
        __syncthreads();
        short8v a[4], b[4];
#pragma unroll
        for (int f = 0; f < 4; ++f)
            a[f] = *(const short8v*)&xs[(wr * 64 + f * 16 + lc) * LDSTR + lg * 8];
#pragma unroll
        for (int f = 0; f < 4; ++f)
            b[f] = *(const short8v*)&es[(wc * 64 + f * 16 + lc) * LDSTR + lg * 8];
#pragma unroll
        for (int i = 0; i < 4; ++i)
#pragma unroll
            for (int j = 0; j < 4; ++j)
                acc[i][j] = __builtin_amdgcn_mfma_f32_16x16x32_bf16(a[i], b[j], acc[i][j], 0, 0, 0);
    }

    // hoist ||e||^2 for this lane's 4 code columns
    float en[4];
#pragma unroll
    for (int j = 0; j < 4; ++j) en[j] = enorm[cbase + wc * 64 + j * 16 + lc];

    // top-2 over this wave's 64-code half (C/D: col=lane&15 code, row=(lane>>4)*4+reg point)
    float bv1[4][4], bv2[4][4]; int bi1[4][4];
#pragma unroll
    for (int i = 0; i < 4; ++i)
#pragma unroll
        for (int r = 0; r < 4; ++r) { bv1[i][r] = 3.4e38f; bv2[i][r] = 3.4e38f; bi1[i][r] = 0; }

#pragma unroll
    for (int j = 0; j < 4; ++j) {
        int cg = cbase + wc * 64 + j * 16 + lc;
#pragma unroll
        for (int i = 0; i < 4; ++i)
#pragma unroll
            for (int r = 0; r < 4; ++r) {
                float d = en[j] - 2.f * acc[i][j][r];
                if (d < bv1[i][r]) { bv2[i][r] = bv1[i][r]; bv1[i][r] = d; bi1[i][r] = cg; }
                else if (d < bv2[i][r]) bv2[i][r] = d;
            }
    }
#pragma unroll
    for (int m = 1; m < 16; m <<= 1) {
#pragma unroll
        for (int i = 0; i < 4; ++i)
#pragma unroll
            for (int r = 0; r < 4; ++r) {
                float o1 = __shfl_xor(bv1[i][r], m);
                float o2 = __shfl_xor(bv2[i][r], m);
                int oi = __shfl_xor(bi1[i][r], m);
                if (o1 < bv1[i][r] || (o1 == bv1[i][r] && oi < bi1[i][r])) {
                    bv2[i][r] = fminf(bv1[i][r], o2);
                    bv1[i][r] = o1; bi1[i][r] = oi;
                } else {
                    bv2[i][r] = fminf(bv2[i][r], o1);
                }
            }
    }

    __syncthreads();
    float* sv1 = (float*)xs;               // [2][128] per-wc mins
    float* sv2 = sv1 + 256;
    int* si1 = (int*)(sv1 + 512);
    if (lc == 0) {
#pragma unroll
        for (int i = 0; i < 4; ++i)
#pragma unroll
            for (int r = 0; r < 4; ++r) {
                int ploc = wr * 64 + i * 16 + lg * 4 + r;
                sv1[wc * 128 + ploc] = bv1[i][r];
                sv2[wc * 128 + ploc] = bv2[i][r];
                si1[wc * 128 + ploc] = bi1[i][r];
            }
    }
    __syncthreads();

    // candidate bitmap: per (point, split), bit (w*32+t) <=> code split*128+w*32+t
#pragma unroll
    for (int i = 0; i < 4; ++i)
#pragma unroll
        for (int r = 0; r < 4; ++r) {
            int ploc = wr * 64 + i * 16 + lg * 4 + r;
            float thr = fminf(sv1[ploc], sv1[128 + ploc]) + MARGIN;
            unsigned int sl[4];
#pragma unroll
            for (int j = 0; j < 4; ++j) {
                float d = en[j] - 2.f * acc[i][j][r];
                unsigned long long m = __ballot(d <= thr);
                sl[j] = (unsigned int)((m >> (lg * 16)) & 0xFFFFull);
            }
            if (lc == 0) {
                size_t base = ((size_t)(pbase + ploc) * NSPLIT + split) * 4 + wc * 2;
                cand[base + 0] = sl[0] | (sl[1] << 16);
                cand[base + 1] = sl[2] | (sl[3] << 16);
            }
        }

    if (tid < 128) {
        float v1 = sv1[tid], v2 = sv2[tid]; int i1 = si1[tid];
        float o1 = sv1[128 + tid], o2 = sv2[128 + tid]; int oi = si1[128 + tid];
        if (o1 < v1 || (o1 == v1 && oi < i1)) {
            v2 = fminf(v1, o2); v1 = o1; i1 = oi;
        } else {
            v2 = fminf(v2, o1);
        }
        size_t p = pbase + tid;
        ws_minv[p * NSPLIT + split] = v1;
        ws_min2[p * NSPLIT + split] = v2;
        ws_midx[p * NSPLIT + split] = i1;
    }
}

// ---------------- phase 2: combine splits, flag ambiguous points ----------------
__global__ void resolve_kernel(const float* __restrict__ ws_minv, const float* __restrict__ ws_min2,
                               const int* __restrict__ ws_midx,
                               int* __restrict__ final_idx, int* __restrict__ list,
                               int* __restrict__ counter) {
    const int p = blockIdx.x * 256 + threadIdx.x;
    float v1 = ws_minv[(size_t)p * NSPLIT];
    float v2 = ws_min2[(size_t)p * NSPLIT];
    int i1 = ws_midx[(size_t)p * NSPLIT];
#pragma unroll
    for (int s = 1; s < NSPLIT; ++s) {
        float b1 = ws_minv[(size_t)p * NSPLIT + s];
        float b2 = ws_min2[(size_t)p * NSPLIT + s];
        int bi = ws_midx[(size_t)p * NSPLIT + s];
        if (b1 < v1 || (b1 == v1 && bi < i1)) {
            v2 = fminf(v1, b2); v1 = b1; i1 = bi;
        } else {
            v2 = fminf(v2, b1);
        }
    }
    final_idx[p] = i1;
    if (v2 - v1 <= MARGIN) {
        int slot = atomicAdd(counter, 1);
        list[slot] = p;
    }
}

// ---------------- phase 3: np-emulating rescore over candidate bitmaps ----------------
// One flagged point per wave. Each lane<32 owns one bitmap word (32 codes);
// per set bit: d = fl32(fl32(A - 2*B) + C), B = sequential ascending-d fp32
// fma chain, A = np-pairwise sum x^2, C = Cnp — bit-identical to rounds 3-6.
__global__ __launch_bounds__(256) void rescore_np_kernel(
        const float* __restrict__ X, const float* __restrict__ E,
        const float* __restrict__ Cnp, const unsigned int* __restrict__ cand,
        const int* __restrict__ list, const int* __restrict__ counter,
        int* __restrict__ final_idx) {
#pragma clang fp contract(off)
    const int tid = threadIdx.x;
    const int lane = tid & 63;
    const int wave = tid >> 6;
    const int cnt = counter[0];
    __shared__ float xsh[4][DIM];

    for (int base = blockIdx.x * 4; base < cnt; base += gridDim.x * 4) {
        const int li = base + wave;
        const bool active = (li < cnt);
        const int p = list[active ? li : (cnt - 1)];
        __syncthreads();
        // stage x row (4 floats/lane)
        *(float4*)&xsh[wave][lane * 4] = *(const float4*)(X + (size_t)p * DIM + lane * 4);
        __syncthreads();

        // A: np-pairwise sum of x^2 (8 accumulators per half, exact combine order)
        float s = 0.f;
        if (lane < 16) {
            const int h = lane >> 3, j = lane & 7;
            float v = xsh[wave][h * 128 + j];
            s = v * v;
            for (int i = 8; i < 128; i += 8) {
                float w = xsh[wave][h * 128 + i + j];
                s += w * w;
            }
        }
        float t0 = __shfl(s, 0), t1 = __shfl(s, 1), t2 = __shfl(s, 2), t3 = __shfl(s, 3);
        float t4 = __shfl(s, 4), t5 = __shfl(s, 5), t6 = __shfl(s, 6), t7 = __shfl(s, 7);
        float u0 = __shfl(s, 8), u1 = __shfl(s, 9), u2 = __shfl(s, 10), u3 = __shfl(s, 11);
        float u4 = __shfl(s, 12), u5 = __shfl(s, 13), u6 = __shfl(s, 14), u7 = __shfl(s, 15);
        const float A = (((t0 + t1) + (t2 + t3)) + ((t4 + t5) + (t6 + t7)))
                      + (((u0 + u1) + (u2 + u3)) + ((u4 + u5) + (u6 + u7)));

        // candidates: lane<32 owns word lane -> codes [(lane>>2)*128 + (lane&3)*32 + t]
        float bv = 3.4e38f; int bi = 0x7FFFFFFF;
        if (lane < 32) {
            unsigned int bits = cand[(size_t)p * 32 + lane];
            const int cb = (lane >> 2) * 128 + (lane & 3) * 32;
            while (bits) {
                int t = __builtin_ctz(bits);
                bits &= bits - 1;
                int c = cb + t;
                const float4* er4 = (const float4*)(E + (size_t)c * DIM);
                float acc = 0.f;
                for (int d4 = 0; d4 < DIM / 4; ++d4) {
                    float4 e4 = er4[d4];
                    float4 x4 = *(const float4*)&xsh[wave][d4 * 4];
                    acc = __builtin_fmaf(x4.x, e4.x, acc);
                    acc = __builtin_fmaf(x4.y, e4.y, acc);
                    acc = __builtin_fmaf(x4.z, e4.z, acc);
                    acc = __builtin_fmaf(x4.w, e4.w, acc);
                }
                float tt = A - 2.0f * acc;      // rounded subtract
                float dnp = tt + Cnp[c];        // rounded add (decisive grid)
                if (dnp < bv) { bv = dnp; bi = c; }   // ascending c -> first occurrence
            }
        }
        // wave argmin with lower-index tie-break
#pragma unroll
        for (int m = 1; m < 64; m <<= 1) {
            float ov = __shfl_xor(bv, m);
            int oi = __shfl_xor(bi, m);
            if (ov < bv || (ov == bv && oi < bi)) { bv = ov; bi = oi; }
        }
        if (active && lane == 0) final_idx[p] = bi;
    }
}

// ---------------- phase 4: gather, write quantized/indices, loss partials ----------------
__global__ void gather_kernel(const float* __restrict__ X, const float* __restrict__ E,
                              const int* __restrict__ final_idx,
                              float* __restrict__ out_q, float* __restrict__ out_idx,
                              float* __restrict__ ws_part) {
    const int tid = threadIdx.x;
    const int p = blockIdx.x * 16 + (tid >> 4);
    const int c = tid & 15;
    const int bi = final_idx[p];

    float ls = 0.f;
#pragma unroll
    for (int k = 0; k < 4; ++k) {
        int d4 = c + k * 16;
        float4 e4 = *(const float4*)(E + (size_t)bi * DIM + d4 * 4);
        float4 x4 = *(const float4*)(X + (size_t)p * DIM + d4 * 4);
        *(float4*)(out_q + (size_t)p * DIM + d4 * 4) = e4;
        float dx = e4.x - x4.x, dy = e4.y - x4.y, dz = e4.z - x4.z, dw = e4.w - x4.w;
        ls += dx * dx + dy * dy + dz * dz + dw * dw;
    }
    if (c == 0) out_idx[p] = (float)bi;

    __shared__ float red[256];
    red[tid] = ls;
    __syncthreads();
#pragma unroll
    for (int s = 128; s > 0; s >>= 1) {
        if (tid < s) red[tid] += red[tid + s];
        __syncthreads();
    }
    if (tid == 0) ws_part[blockIdx.x] = red[0];
}

// ---------------- phase 5: final loss reduce ----------------
__global__ void loss_kernel(const float* __restrict__ ws_part, float* __restrict__ out_loss) {
    const int tid = threadIdx.x;
    float s = 0.f;
    for (int i = tid; i < NPTS / 16; i += 256) s += ws_part[i];
    __shared__ float red[256];
    red[tid] = s;
    __syncthreads();
#pragma unroll
    for (int t = 128; t > 0; t >>= 1) {
        if (tid < t) red[tid] += red[tid + t];
        __syncthreads();
    }
    if (tid == 0)
        out_loss[0] = (1.f + 0.25f) * red[0] / (float)((size_t)NPTS * DIM);
}

extern "C" void kernel_launch(void* const* d_in, const int* in_sizes, int n_in,
                              void* d_out, int out_size, void* d_ws, size_t ws_size,
                              hipStream_t stream) {
    const float* X = (const float*)d_in[0];   // [32768, 256]
    const float* E = (const float*)d_in[1];   // [1024, 256]
    float* out = (float*)d_out;
    float* out_q = out;                                 // 8388608 floats
    float* out_loss = out + (size_t)NPTS * DIM;         // 1 float
    float* out_idx = out + (size_t)NPTS * DIM + 1;      // 32768 floats

    // staging inside out_q (rewritten by gather afterward):
    // Xb (16.8MB) + Eb (0.5MB) + cand (4.2MB) = 21.5MB < 33.5MB
    unsigned short* Xb = (unsigned short*)d_out;
    unsigned short* Eb = Xb + (size_t)NPTS * DIM;
    unsigned int* cand = (unsigned int*)(Eb + (size_t)KCODES * DIM);  // [NPTS][8][4] u32

    float* ws = (float*)d_ws;
    float* enorm = ws;                                  // 1024
    float* Cnp = enorm + KCODES;                        // 1024
    float* ws_minv = Cnp + KCODES;                      // 32768*8
    float* ws_min2 = ws_minv + (size_t)NPTS * NSPLIT;   // 32768*8
    int* ws_midx = (int*)(ws_min2 + (size_t)NPTS * NSPLIT);  // 32768*8 ints
    int* final_idx = ws_midx + (size_t)NPTS * NSPLIT;   // 32768 ints
    int* counter = final_idx + NPTS;                    // 1 int (+63 pad)
    int* list = counter + 64;                           // 32768 ints
    float* ws_part = (float*)(list + NPTS);             // 2048 floats

    convert_kernel<<<(NPTS + KCODES) * DIM / 8 / 256, 256, 0, stream>>>(X, E, Xb, Eb);
    enorm_kernel<<<KCODES / 4, 256, 0, stream>>>(E, enorm, counter);
    enormnp_kernel<<<KCODES / 256, 256, 0, stream>>>(E, Cnp);
    dist_kernel<<<dim3(NPTS / BN, NSPLIT), 256, 0, stream>>>(Xb, Eb, enorm,
                                                             ws_minv, ws_min2, ws_midx, cand);
    resolve_kernel<<<NPTS / 256, 256, 0, stream>>>(ws_minv, ws_min2, ws_midx,
                                                   final_idx, list, counter);
    rescore_np_kernel<<<512, 256, 0, stream>>>(X, E, Cnp, cand, list, counter, final_idx);
    gather_kernel<<<NPTS / 16, 256, 0, stream>>>(X, E, final_idx, out_q, out_idx, ws_part);
    loss_kernel<<<1, 256, 0, stream>>>(ws_part, out_loss);
}

// Round 8
// 125.908 us; speedup vs baseline: 1.4739x; 1.0593x over previous
//
#include <hip/hip_runtime.h>

#define NPTS 32768
#define DIM 256
#define KCODES 1024
#define NSPLIT 8                 // code-splits in the MFMA screen (128 codes/block)
#define BN 128                   // points per screen block
#define BKC 128                  // codes per screen block
#define BK 64                    // K-step (bf16) per staging iter
#define MARGIN 0.08f             // bf16 top-2 gap band: flag + candidate threshold

typedef __attribute__((ext_vector_type(8))) short short8v;
typedef __attribute__((ext_vector_type(8))) unsigned short ushort8v;
typedef __attribute__((ext_vector_type(4))) float f32x4;

static __device__ __forceinline__ unsigned short f2bf(float f) {
    unsigned int u = __float_as_uint(f);
    unsigned int r = (u + 0x7fffu + ((u >> 16) & 1u)) >> 16;   // RNE
    return (unsigned short)r;
}

static __device__ __forceinline__ void gload16(const void* g, void* l) {
    __builtin_amdgcn_global_load_lds((const __attribute__((address_space(1))) void*)g,
                                     (__attribute__((address_space(3))) void*)l, 16, 0, 0);
}

// ---------------- phase -1: f32 -> bf16 conversion of X and E ----------------
__global__ void convert_kernel(const float* __restrict__ X, const float* __restrict__ E,
                               unsigned short* __restrict__ Xb, unsigned short* __restrict__ Eb) {
    int i = blockIdx.x * 256 + threadIdx.x;
    size_t e8 = (size_t)i * 8;
    const float* src; unsigned short* dst; size_t off;
    if (e8 < (size_t)NPTS * DIM) { src = X; dst = Xb; off = e8; }
    else { src = E; dst = Eb; off = e8 - (size_t)NPTS * DIM; }
    float4 f0 = *(const float4*)(src + off);
    float4 f1 = *(const float4*)(src + off + 4);
    ushort8v v;
    v[0] = f2bf(f0.x); v[1] = f2bf(f0.y); v[2] = f2bf(f0.z); v[3] = f2bf(f0.w);
    v[4] = f2bf(f1.x); v[5] = f2bf(f1.y); v[6] = f2bf(f1.z); v[7] = f2bf(f1.w);
    *(ushort8v*)(dst + off) = v;
}

// ---------------- phase 0a: fast fp32 embedding norms (screening) ----------------
__global__ void enorm_kernel(const float* __restrict__ E, float* __restrict__ enorm,
                             int* __restrict__ counter) {
    if (blockIdx.x == 0 && threadIdx.x == 0) counter[0] = 0;
    int wave = threadIdx.x >> 6;
    int lane = threadIdx.x & 63;
    int k = blockIdx.x * 4 + wave;
    float4 v = *(const float4*)(E + (size_t)k * DIM + lane * 4);
    float s = v.x * v.x + v.y * v.y + v.z * v.z + v.w * v.w;
#pragma unroll
    for (int m = 32; m >= 1; m >>= 1) s += __shfl_xor(s, m);
    if (lane == 0) enorm[k] = s;
}

// ---------------- phase 0b: numpy-faithful ||e||^2 (pairwise emulation) ----------------
__global__ void enormnp_kernel(const float* __restrict__ E, float* __restrict__ Cnp) {
#pragma clang fp contract(off)
    int k = blockIdx.x * 256 + threadIdx.x;
    const float* e = E + (size_t)k * DIM;
    float half[2];
    for (int h = 0; h < 2; ++h) {
        const float* b = e + h * 128;
        float s[8];
#pragma unroll
        for (int j = 0; j < 8; ++j) { float v = b[j]; s[j] = v * v; }
        for (int i = 8; i < 128; i += 8) {
#pragma unroll
            for (int j = 0; j < 8; ++j) { float v = b[i + j]; s[j] += v * v; }
        }
        half[h] = ((s[0] + s[1]) + (s[2] + s[3])) + ((s[4] + s[5]) + (s[6] + s[7]));
    }
    Cnp[k] = half[0] + half[1];
}

// ---------------- phase 1: bf16-MFMA screen (m97-style staging) ----------------
// grid (NPTS/128, 8 splits), 256 threads = 4 waves (2x2 of 64x64 MFMA tiles).
// LDS tiles [128][64] bf16 LINEAR (128B rows), staged via global_load_lds w=16
// with XOR-swizzled per-lane global source (c16' = c16 ^ (row&7)); ds_read uses
// the same swizzle -> conflict-free fragment reads (rule #21 both-sides).
__global__ __launch_bounds__(256, 3) void dist_kernel(
        const unsigned short* __restrict__ Xb, const unsigned short* __restrict__ Eb,
        const float* __restrict__ enorm,
        float* __restrict__ ws_minv, float* __restrict__ ws_min2,
        int* __restrict__ ws_midx, unsigned int* __restrict__ cand) {
    __shared__ unsigned short xs[BN * BK];    // 16 KB
    __shared__ unsigned short es[BKC * BK];   // 16 KB

    const int tid = threadIdx.x;
    const int lane = tid & 63;
    const int wave = tid >> 6;
    const int wr = wave >> 1, wc = wave & 1;
    const int lg = lane >> 4, lc = lane & 15;
    const int pbase = blockIdx.x * BN;
    const int split = blockIdx.y;
    const int cbase = split * BKC;

    f32x4 acc[4][4];
#pragma unroll
    for (int i = 0; i < 4; ++i)
#pragma unroll
        for (int j = 0; j < 4; ++j) acc[i][j] = (f32x4){0.f, 0.f, 0.f, 0.f};

    for (int ks = 0; ks < DIM / BK; ++ks) {
        const int k0 = ks * BK;
        __syncthreads();
        // stage both tiles: 8 gload_lds per wave (4 X + 4 E), 1 KB each
#pragma unroll
        for (int i = 0; i < 4; ++i) {
            const int B = wave * 4096 + i * 1024 + lane * 16;   // byte offset in tile
            const int row = B >> 7;                             // 128B rows
            const int c16 = (B >> 4) & 7;
            const int cs = c16 ^ (row & 7);                     // inverse swizzle on source
            gload16(Xb + (size_t)(pbase + row) * DIM + k0 + cs * 8,
                    (char*)xs + wave * 4096 + i * 1024);
            gload16(Eb + (size_t)(cbase + row) * DIM + k0 + cs * 8,
                    (char*)es + wave * 4096 + i * 1024);
        }
        __syncthreads();
#pragma unroll
        for (int kk = 0; kk < 2; ++kk) {
            short8v a[4], b[4];
#pragma unroll
            for (int f = 0; f < 4; ++f) {
                int row = wr * 64 + f * 16 + lc;
                int cs = (kk * 4 + lg) ^ (row & 7);             // swizzled read
                a[f] = *(const short8v*)&xs[row * BK + cs * 8];
            }
#pragma unroll
            for (int f = 0; f < 4; ++f) {
                int row = wc * 64 + f * 16 + lc;
                int cs = (kk * 4 + lg) ^ (row & 7);
                b[f] = *(const short8v*)&es[row * BK + cs * 8];
            }
#pragma unroll
            for (int i = 0; i < 4; ++i)
#pragma unroll
                for (int j = 0; j < 4; ++j)
                    acc[i][j] = __builtin_amdgcn_mfma_f32_16x16x32_bf16(a[i], b[j], acc[i][j], 0, 0, 0);
        }
    }

    // hoist ||e||^2 for this lane's 4 code columns
    float en[4];
#pragma unroll
    for (int j = 0; j < 4; ++j) en[j] = enorm[cbase + wc * 64 + j * 16 + lc];

    // top-2 over this wave's 64-code half (C/D: col=lane&15 code, row=(lane>>4)*4+reg point)
    float bv1[4][4], bv2[4][4]; int bi1[4][4];
#pragma unroll
    for (int i = 0; i < 4; ++i)
#pragma unroll
        for (int r = 0; r < 4; ++r) { bv1[i][r] = 3.4e38f; bv2[i][r] = 3.4e38f; bi1[i][r] = 0; }

#pragma unroll
    for (int j = 0; j < 4; ++j) {
        int cg = cbase + wc * 64 + j * 16 + lc;
#pragma unroll
        for (int i = 0; i < 4; ++i)
#pragma unroll
            for (int r = 0; r < 4; ++r) {
                float d = en[j] - 2.f * acc[i][j][r];
                if (d < bv1[i][r]) { bv2[i][r] = bv1[i][r]; bv1[i][r] = d; bi1[i][r] = cg; }
                else if (d < bv2[i][r]) bv2[i][r] = d;
            }
    }
#pragma unroll
    for (int m = 1; m < 16; m <<= 1) {
#pragma unroll
        for (int i = 0; i < 4; ++i)
#pragma unroll
            for (int r = 0; r < 4; ++r) {
                float o1 = __shfl_xor(bv1[i][r], m);
                float o2 = __shfl_xor(bv2[i][r], m);
                int oi = __shfl_xor(bi1[i][r], m);
                if (o1 < bv1[i][r] || (o1 == bv1[i][r] && oi < bi1[i][r])) {
                    bv2[i][r] = fminf(bv1[i][r], o2);
                    bv1[i][r] = o1; bi1[i][r] = oi;
                } else {
                    bv2[i][r] = fminf(bv2[i][r], o1);
                }
            }
    }

    __syncthreads();
    float* sv1 = (float*)xs;               // [2][128] per-wc mins
    float* sv2 = sv1 + 256;
    int* si1 = (int*)(sv1 + 512);
    if (lc == 0) {
#pragma unroll
        for (int i = 0; i < 4; ++i)
#pragma unroll
            for (int r = 0; r < 4; ++r) {
                int ploc = wr * 64 + i * 16 + lg * 4 + r;
                sv1[wc * 128 + ploc] = bv1[i][r];
                sv2[wc * 128 + ploc] = bv2[i][r];
                si1[wc * 128 + ploc] = bi1[i][r];
            }
    }
    __syncthreads();

    // candidate bitmap: per (point, split), bit (w*32+t) <=> code split*128+w*32+t
#pragma unroll
    for (int i = 0; i < 4; ++i)
#pragma unroll
        for (int r = 0; r < 4; ++r) {
            int ploc = wr * 64 + i * 16 + lg * 4 + r;
            float thr = fminf(sv1[ploc], sv1[128 + ploc]) + MARGIN;
            unsigned int sl[4];
#pragma unroll
            for (int j = 0; j < 4; ++j) {
                float d = en[j] - 2.f * acc[i][j][r];
                unsigned long long m = __ballot(d <= thr);
                sl[j] = (unsigned int)((m >> (lg * 16)) & 0xFFFFull);
            }
            if (lc == 0) {
                size_t base = ((size_t)(pbase + ploc) * NSPLIT + split) * 4 + wc * 2;
                cand[base + 0] = sl[0] | (sl[1] << 16);
                cand[base + 1] = sl[2] | (sl[3] << 16);
            }
        }

    if (tid < 128) {
        float v1 = sv1[tid], v2 = sv2[tid]; int i1 = si1[tid];
        float o1 = sv1[128 + tid], o2 = sv2[128 + tid]; int oi = si1[128 + tid];
        if (o1 < v1 || (o1 == v1 && oi < i1)) {
            v2 = fminf(v1, o2); v1 = o1; i1 = oi;
        } else {
            v2 = fminf(v2, o1);
        }
        size_t p = pbase + tid;
        ws_minv[p * NSPLIT + split] = v1;
        ws_min2[p * NSPLIT + split] = v2;
        ws_midx[p * NSPLIT + split] = i1;
    }
}

// ---------------- phase 2: combine splits, flag ambiguous points ----------------
__global__ void resolve_kernel(const float* __restrict__ ws_minv, const float* __restrict__ ws_min2,
                               const int* __restrict__ ws_midx,
                               int* __restrict__ final_idx, int* __restrict__ list,
                               int* __restrict__ counter) {
    const int p = blockIdx.x * 256 + threadIdx.x;
    float v1 = ws_minv[(size_t)p * NSPLIT];
    float v2 = ws_min2[(size_t)p * NSPLIT];
    int i1 = ws_midx[(size_t)p * NSPLIT];
#pragma unroll
    for (int s = 1; s < NSPLIT; ++s) {
        float b1 = ws_minv[(size_t)p * NSPLIT + s];
        float b2 = ws_min2[(size_t)p * NSPLIT + s];
        int bi = ws_midx[(size_t)p * NSPLIT + s];
        if (b1 < v1 || (b1 == v1 && bi < i1)) {
            v2 = fminf(v1, b2); v1 = b1; i1 = bi;
        } else {
            v2 = fminf(v2, b1);
        }
    }
    final_idx[p] = i1;
    if (v2 - v1 <= MARGIN) {
        int slot = atomicAdd(counter, 1);
        list[slot] = p;
    }
}

// ---------------- phase 3: np-emulating rescore over candidate bitmaps ----------------
__global__ __launch_bounds__(256) void rescore_np_kernel(
        const float* __restrict__ X, const float* __restrict__ E,
        const float* __restrict__ Cnp, const unsigned int* __restrict__ cand,
        const int* __restrict__ list, const int* __restrict__ counter,
        int* __restrict__ final_idx) {
#pragma clang fp contract(off)
    const int tid = threadIdx.x;
    const int lane = tid & 63;
    const int wave = tid >> 6;
    const int cnt = counter[0];
    __shared__ float xsh[4][DIM];

    for (int base = blockIdx.x * 4; base < cnt; base += gridDim.x * 4) {
        const int li = base + wave;
        const bool active = (li < cnt);
        const int p = list[active ? li : (cnt - 1)];
        __syncthreads();
        *(float4*)&xsh[wave][lane * 4] = *(const float4*)(X + (size_t)p * DIM + lane * 4);
        __syncthreads();

        // A: np-pairwise sum of x^2 (8 accumulators per half, exact combine order)
        float s = 0.f;
        if (lane < 16) {
            const int h = lane >> 3, j = lane & 7;
            float v = xsh[wave][h * 128 + j];
            s = v * v;
            for (int i = 8; i < 128; i += 8) {
                float w = xsh[wave][h * 128 + i + j];
                s += w * w;
            }
        }
        float t0 = __shfl(s, 0), t1 = __shfl(s, 1), t2 = __shfl(s, 2), t3 = __shfl(s, 3);
        float t4 = __shfl(s, 4), t5 = __shfl(s, 5), t6 = __shfl(s, 6), t7 = __shfl(s, 7);
        float u0 = __shfl(s, 8), u1 = __shfl(s, 9), u2 = __shfl(s, 10), u3 = __shfl(s, 11);
        float u4 = __shfl(s, 12), u5 = __shfl(s, 13), u6 = __shfl(s, 14), u7 = __shfl(s, 15);
        const float A = (((t0 + t1) + (t2 + t3)) + ((t4 + t5) + (t6 + t7)))
                      + (((u0 + u1) + (u2 + u3)) + ((u4 + u5) + (u6 + u7)));

        float bv = 3.4e38f; int bi = 0x7FFFFFFF;
        if (lane < 32) {
            unsigned int bits = cand[(size_t)p * 32 + lane];
            const int cb = (lane >> 2) * 128 + (lane & 3) * 32;
            while (bits) {
                int t = __builtin_ctz(bits);
                bits &= bits - 1;
                int c = cb + t;
                const float4* er4 = (const float4*)(E + (size_t)c * DIM);
                float acc = 0.f;
                for (int d4 = 0; d4 < DIM / 4; ++d4) {
                    float4 e4 = er4[d4];
                    float4 x4 = *(const float4*)&xsh[wave][d4 * 4];
                    acc = __builtin_fmaf(x4.x, e4.x, acc);
                    acc = __builtin_fmaf(x4.y, e4.y, acc);
                    acc = __builtin_fmaf(x4.z, e4.z, acc);
                    acc = __builtin_fmaf(x4.w, e4.w, acc);
                }
                float tt = A - 2.0f * acc;      // rounded subtract
                float dnp = tt + Cnp[c];        // rounded add (decisive grid)
                if (dnp < bv) { bv = dnp; bi = c; }
            }
        }
#pragma unroll
        for (int m = 1; m < 64; m <<= 1) {
            float ov = __shfl_xor(bv, m);
            int oi = __shfl_xor(bi, m);
            if (ov < bv || (ov == bv && oi < bi)) { bv = ov; bi = oi; }
        }
        if (active && lane == 0) final_idx[p] = bi;
    }
}

// ---------------- phase 4: gather, write quantized/indices, loss partials ----------------
__global__ void gather_kernel(const float* __restrict__ X, const float* __restrict__ E,
                              const int* __restrict__ final_idx,
                              float* __restrict__ out_q, float* __restrict__ out_idx,
                              float* __restrict__ ws_part) {
    const int tid = threadIdx.x;
    const int p = blockIdx.x * 16 + (tid >> 4);
    const int c = tid & 15;
    const int bi = final_idx[p];

    float ls = 0.f;
#pragma unroll
    for (int k = 0; k < 4; ++k) {
        int d4 = c + k * 16;
        float4 e4 = *(const float4*)(E + (size_t)bi * DIM + d4 * 4);
        float4 x4 = *(const float4*)(X + (size_t)p * DIM + d4 * 4);
        *(float4*)(out_q + (size_t)p * DIM + d4 * 4) = e4;
        float dx = e4.x - x4.x, dy = e4.y - x4.y, dz = e4.z - x4.z, dw = e4.w - x4.w;
        ls += dx * dx + dy * dy + dz * dz + dw * dw;
    }
    if (c == 0) out_idx[p] = (float)bi;

    __shared__ float red[256];
    red[tid] = ls;
    __syncthreads();
#pragma unroll
    for (int s = 128; s > 0; s >>= 1) {
        if (tid < s) red[tid] += red[tid + s];
        __syncthreads();
    }
    if (tid == 0) ws_part[blockIdx.x] = red[0];
}

// ---------------- phase 5: final loss reduce ----------------
__global__ void loss_kernel(const float* __restrict__ ws_part, float* __restrict__ out_loss) {
    const int tid = threadIdx.x;
    float s = 0.f;
    for (int i = tid; i < NPTS / 16; i += 256) s += ws_part[i];
    __shared__ float red[256];
    red[tid] = s;
    __syncthreads();
#pragma unroll
    for (int t = 128; t > 0; t >>= 1) {
        if (tid < t) red[tid] += red[tid + t];
        __syncthreads();
    }
    if (tid == 0)
        out_loss[0] = (1.f + 0.25f) * red[0] / (float)((size_t)NPTS * DIM);
}

extern "C" void kernel_launch(void* const* d_in, const int* in_sizes, int n_in,
                              void* d_out, int out_size, void* d_ws, size_t ws_size,
                              hipStream_t stream) {
    const float* X = (const float*)d_in[0];   // [32768, 256]
    const float* E = (const float*)d_in[1];   // [1024, 256]
    float* out = (float*)d_out;
    float* out_q = out;                                 // 8388608 floats
    float* out_loss = out + (size_t)NPTS * DIM;         // 1 float
    float* out_idx = out + (size_t)NPTS * DIM + 1;      // 32768 floats

    // staging inside out_q (rewritten by gather afterward):
    // Xb (16.8MB) + Eb (0.5MB) + cand (4.2MB) = 21.5MB < 33.5MB
    unsigned short* Xb = (unsigned short*)d_out;
    unsigned short* Eb = Xb + (size_t)NPTS * DIM;
    unsigned int* cand = (unsigned int*)(Eb + (size_t)KCODES * DIM);  // [NPTS][8][4] u32

    float* ws = (float*)d_ws;
    float* enorm = ws;                                  // 1024
    float* Cnp = enorm + KCODES;                        // 1024
    float* ws_minv = Cnp + KCODES;                      // 32768*8
    float* ws_min2 = ws_minv + (size_t)NPTS * NSPLIT;   // 32768*8
    int* ws_midx = (int*)(ws_min2 + (size_t)NPTS * NSPLIT);  // 32768*8 ints
    int* final_idx = ws_midx + (size_t)NPTS * NSPLIT;   // 32768 ints
    int* counter = final_idx + NPTS;                    // 1 int (+63 pad)
    int* list = counter + 64;                           // 32768 ints
    float* ws_part = (float*)(list + NPTS);             // 2048 floats

    convert_kernel<<<(NPTS + KCODES) * DIM / 8 / 256, 256, 0, stream>>>(X, E, Xb, Eb);
    enorm_kernel<<<KCODES / 4, 256, 0, stream>>>(E, enorm, counter);
    enormnp_kernel<<<KCODES / 256, 256, 0, stream>>>(E, Cnp);
    dist_kernel<<<dim3(NPTS / BN, NSPLIT), 256, 0, stream>>>(Xb, Eb, enorm,
                                                             ws_minv, ws_min2, ws_midx, cand);
    resolve_kernel<<<NPTS / 256, 256, 0, stream>>>(ws_minv, ws_min2, ws_midx,
                                                   final_idx, list, counter);
    rescore_np_kernel<<<512, 256, 0, stream>>>(X, E, Cnp, cand, list, counter, final_idx);
    gather_kernel<<<NPTS / 16, 256, 0, stream>>>(X, E, final_idx, out_q, out_idx, ws_part);
    loss_kernel<<<1, 256, 0, stream>>>(ws_part, out_loss);
}

// Round 9
// 98.202 us; speedup vs baseline: 1.8897x; 1.2821x over previous
//
#include <hip/hip_runtime.h>

#define NPTS 32768
#define DIM 256
#define KCODES 1024
#define NSPLIT 8                 // code-splits in the MFMA screen (128 codes/block)
#define BN 256                   // points per screen block
#define BKC 128                  // codes per screen block
#define BK 64                    // K-step (bf16) per staging iter
#define MARGIN 0.08f             // bf16 band: flag + candidate threshold

typedef __attribute__((ext_vector_type(8))) short short8v;
typedef __attribute__((ext_vector_type(8))) unsigned short ushort8v;
typedef __attribute__((ext_vector_type(4))) float f32x4;

static __device__ __forceinline__ unsigned short f2bf(float f) {
    unsigned int u = __float_as_uint(f);
    unsigned int r = (u + 0x7fffu + ((u >> 16) & 1u)) >> 16;   // RNE
    return (unsigned short)r;
}

static __device__ __forceinline__ void gload16(const void* g, void* l) {
    __builtin_amdgcn_global_load_lds((const __attribute__((address_space(1))) void*)g,
                                     (__attribute__((address_space(3))) void*)l, 16, 0, 0);
}

// ---------------- phase -1: f32 -> bf16 conversion of X and E ----------------
__global__ void convert_kernel(const float* __restrict__ X, const float* __restrict__ E,
                               unsigned short* __restrict__ Xb, unsigned short* __restrict__ Eb) {
    int i = blockIdx.x * 256 + threadIdx.x;
    size_t e8 = (size_t)i * 8;
    const float* src; unsigned short* dst; size_t off;
    if (e8 < (size_t)NPTS * DIM) { src = X; dst = Xb; off = e8; }
    else { src = E; dst = Eb; off = e8 - (size_t)NPTS * DIM; }
    float4 f0 = *(const float4*)(src + off);
    float4 f1 = *(const float4*)(src + off + 4);
    ushort8v v;
    v[0] = f2bf(f0.x); v[1] = f2bf(f0.y); v[2] = f2bf(f0.z); v[3] = f2bf(f0.w);
    v[4] = f2bf(f1.x); v[5] = f2bf(f1.y); v[6] = f2bf(f1.z); v[7] = f2bf(f1.w);
    *(ushort8v*)(dst + off) = v;
}

// ---------------- phase 0: numpy-faithful ||e||^2 (pairwise emulation) + counter zero ----------------
__global__ void enormnp_kernel(const float* __restrict__ E, float* __restrict__ Cnp,
                               int* __restrict__ counter) {
#pragma clang fp contract(off)
    if (blockIdx.x == 0 && threadIdx.x == 0) counter[0] = 0;
    int k = blockIdx.x * 256 + threadIdx.x;
    const float* e = E + (size_t)k * DIM;
    float half[2];
    for (int h = 0; h < 2; ++h) {
        const float* b = e + h * 128;
        float s[8];
#pragma unroll
        for (int j = 0; j < 8; ++j) { float v = b[j]; s[j] = v * v; }
        for (int i = 8; i < 128; i += 8) {
#pragma unroll
            for (int j = 0; j < 8; ++j) { float v = b[i + j]; s[j] += v * v; }
        }
        half[h] = ((s[0] + s[1]) + (s[2] + s[3])) + ((s[4] + s[5]) + (s[6] + s[7]));
    }
    Cnp[k] = half[0] + half[1];
}

// ---------------- phase 1: bf16-MFMA screen — value-only top-2 + candidate bitmaps ----------------
// grid (NPTS/256, 8 splits), 256 threads = 4 waves; wave w owns points
// [w*64, w*64+64) x all 128 codes (no cross-wave combine). LDS linear tiles,
// gload_lds w=16 with XOR-swizzled global source; swizzled ds_read (rule #21).
__global__ __launch_bounds__(256, 2) void dist_kernel(
        const unsigned short* __restrict__ Xb, const unsigned short* __restrict__ Eb,
        const float* __restrict__ Cnp,
        float* __restrict__ ws_mm, unsigned int* __restrict__ cand) {
    __shared__ unsigned short xs[BN * BK];    // 32 KB
    __shared__ unsigned short es[BKC * BK];   // 16 KB

    const int tid = threadIdx.x;
    const int lane = tid & 63;
    const int wave = tid >> 6;
    const int lg = lane >> 4, lc = lane & 15;
    const int pbase = blockIdx.x * BN;
    const int split = blockIdx.y;
    const int cbase = split * BKC;

    f32x4 acc[4][8];
#pragma unroll
    for (int i = 0; i < 4; ++i)
#pragma unroll
        for (int j = 0; j < 8; ++j) acc[i][j] = (f32x4){0.f, 0.f, 0.f, 0.f};

    for (int ks = 0; ks < DIM / BK; ++ks) {
        const int k0 = ks * BK;
        __syncthreads();
        // X tile: 8 KB per wave (rows w*64..), 8 gload16
#pragma unroll
        for (int q = 0; q < 8; ++q) {
            const int B = wave * 8192 + q * 1024 + lane * 16;
            const int row = B >> 7;
            const int cs = ((B >> 4) & 7) ^ (row & 7);
            gload16(Xb + (size_t)(pbase + row) * DIM + k0 + cs * 8,
                    (char*)xs + wave * 8192 + q * 1024);
        }
        // E tile: 4 KB per wave, 4 gload16
#pragma unroll
        for (int q = 0; q < 4; ++q) {
            const int B = wave * 4096 + q * 1024 + lane * 16;
            const int row = B >> 7;
            const int cs = ((B >> 4) & 7) ^ (row & 7);
            gload16(Eb + (size_t)(cbase + row) * DIM + k0 + cs * 8,
                    (char*)es + wave * 4096 + q * 1024);
        }
        __syncthreads();
#pragma unroll
        for (int kk = 0; kk < 2; ++kk) {
            short8v a[4];
#pragma unroll
            for (int f = 0; f < 4; ++f) {
                int row = wave * 64 + f * 16 + lc;
                int cs = (kk * 4 + lg) ^ (row & 7);
                a[f] = *(const short8v*)&xs[row * BK + cs * 8];
            }
#pragma unroll
            for (int j = 0; j < 8; ++j) {
                int row = j * 16 + lc;
                int cs = (kk * 4 + lg) ^ (row & 7);
                short8v b = *(const short8v*)&es[row * BK + cs * 8];
#pragma unroll
                for (int i = 0; i < 4; ++i)
                    acc[i][j] = __builtin_amdgcn_mfma_f32_16x16x32_bf16(a[i], b, acc[i][j], 0, 0, 0);
            }
        }
    }

    // ||e||^2 for this lane's 8 code columns
    float en8[8];
#pragma unroll
    for (int j = 0; j < 8; ++j) en8[j] = Cnp[cbase + j * 16 + lc];

    // value-only top-2 per point (C/D: col=lane&15 code, row=(lane>>4)*4+reg point)
    float m1[4][4], m2[4][4];
#pragma unroll
    for (int i = 0; i < 4; ++i)
#pragma unroll
        for (int r = 0; r < 4; ++r) { m1[i][r] = 3.4e38f; m2[i][r] = 3.4e38f; }

#pragma unroll
    for (int j = 0; j < 8; ++j)
#pragma unroll
        for (int i = 0; i < 4; ++i)
#pragma unroll
            for (int r = 0; r < 4; ++r) {
                float d = __builtin_fmaf(-2.f, acc[i][j][r], en8[j]);
                m2[i][r] = fminf(fmaxf(d, m1[i][r]), m2[i][r]);   // med3 idiom
                m1[i][r] = fminf(d, m1[i][r]);
            }

    // value-only top-2 merge across the 16 code-lanes sharing a point
#pragma unroll
    for (int m = 1; m < 16; m <<= 1) {
#pragma unroll
        for (int i = 0; i < 4; ++i)
#pragma unroll
            for (int r = 0; r < 4; ++r) {
                float o1 = __shfl_xor(m1[i][r], m);
                float o2 = __shfl_xor(m2[i][r], m);
                float mx = fmaxf(m1[i][r], o1);
                m1[i][r] = fminf(m1[i][r], o1);
                m2[i][r] = fminf(fminf(m2[i][r], o2), mx);
            }
    }

    // candidate bitmaps: bit set iff d <= fl(m1 + MARGIN); pack 128 bits -> uint4
#pragma unroll
    for (int i = 0; i < 4; ++i)
#pragma unroll
        for (int r = 0; r < 4; ++r) {
            float thr = m1[i][r] + MARGIN;
            unsigned int sl[8];
#pragma unroll
            for (int j = 0; j < 8; ++j) {
                float d = __builtin_fmaf(-2.f, acc[i][j][r], en8[j]);
                unsigned long long mm = __ballot(d <= thr);
                sl[j] = (unsigned int)((mm >> (lg * 16)) & 0xFFFFull);
            }
            if (lc == 0) {
                int p = pbase + wave * 64 + i * 16 + lg * 4 + r;
                uint4 w4 = { sl[0] | (sl[1] << 16), sl[2] | (sl[3] << 16),
                             sl[4] | (sl[5] << 16), sl[6] | (sl[7] << 16) };
                *(uint4*)&cand[((size_t)p * NSPLIT + split) * 4] = w4;
                float2 mm2 = { m1[i][r], m2[i][r] };
                *(float2*)&ws_mm[((size_t)p * NSPLIT + split) * 2] = mm2;
            }
        }
}

// ---------------- phase 2: combine splits, derive index, flag ambiguous ----------------
__global__ void resolve_kernel(const float* __restrict__ ws_mm, const unsigned int* __restrict__ cand,
                               int* __restrict__ final_idx, int* __restrict__ list,
                               int* __restrict__ counter) {
    const int p = blockIdx.x * 256 + threadIdx.x;
    float v1 = 3.4e38f, v2 = 3.4e38f;
    int sstar = 0;
#pragma unroll
    for (int s = 0; s < NSPLIT; ++s) {
        float2 mm = *(const float2*)&ws_mm[((size_t)p * NSPLIT + s) * 2];
        if (mm.x < v1) {
            v2 = fminf(v1, mm.y); v1 = mm.x; sstar = s;
        } else {
            v2 = fminf(v2, mm.x);
        }
    }
    // index = lowest set bit of winning split's bitmap (unique when unflagged)
    uint4 w4 = *(const uint4*)&cand[((size_t)p * NSPLIT + sstar) * 4];
    int idx;
    if (w4.x)      idx = __builtin_ctz(w4.x);
    else if (w4.y) idx = 32 + __builtin_ctz(w4.y);
    else if (w4.z) idx = 64 + __builtin_ctz(w4.z);
    else           idx = 96 + __builtin_ctz(w4.w);
    final_idx[p] = sstar * BKC + idx;

    float thr = v1 + MARGIN;            // same rounded op as dist's bitmap threshold
    if (v2 <= thr) {
        int slot = atomicAdd(counter, 1);
        list[slot] = p;
    }
}

// ---------------- phase 3: np-emulating rescore over candidate bitmaps ----------------
// One flagged point per wave; lane<32 owns one bitmap word (32 codes); per set
// bit: d = fl32(fl32(A - 2*B) + C), B = sequential ascending-d fp32 fma chain,
// A = np-pairwise sum x^2, C = Cnp — bit-identical to rounds 3-8.
__global__ __launch_bounds__(256) void rescore_np_kernel(
        const float* __restrict__ X, const float* __restrict__ E,
        const float* __restrict__ Cnp, const unsigned int* __restrict__ cand,
        const int* __restrict__ list, const int* __restrict__ counter,
        int* __restrict__ final_idx) {
#pragma clang fp contract(off)
    const int tid = threadIdx.x;
    const int lane = tid & 63;
    const int wave = tid >> 6;
    const int cnt = counter[0];
    __shared__ float xsh[4][DIM];

    for (int base = blockIdx.x * 4; base < cnt; base += gridDim.x * 4) {
        const int li = base + wave;
        const bool active = (li < cnt);
        const int p = list[active ? li : (cnt - 1)];
        __syncthreads();
        *(float4*)&xsh[wave][lane * 4] = *(const float4*)(X + (size_t)p * DIM + lane * 4);
        __syncthreads();

        // A: np-pairwise sum of x^2 (8 accumulators per half, exact combine order)
        float s = 0.f;
        if (lane < 16) {
            const int h = lane >> 3, j = lane & 7;
            float v = xsh[wave][h * 128 + j];
            s = v * v;
            for (int i = 8; i < 128; i += 8) {
                float w = xsh[wave][h * 128 + i + j];
                s += w * w;
            }
        }
        float t0 = __shfl(s, 0), t1 = __shfl(s, 1), t2 = __shfl(s, 2), t3 = __shfl(s, 3);
        float t4 = __shfl(s, 4), t5 = __shfl(s, 5), t6 = __shfl(s, 6), t7 = __shfl(s, 7);
        float u0 = __shfl(s, 8), u1 = __shfl(s, 9), u2 = __shfl(s, 10), u3 = __shfl(s, 11);
        float u4 = __shfl(s, 12), u5 = __shfl(s, 13), u6 = __shfl(s, 14), u7 = __shfl(s, 15);
        const float A = (((t0 + t1) + (t2 + t3)) + ((t4 + t5) + (t6 + t7)))
                      + (((u0 + u1) + (u2 + u3)) + ((u4 + u5) + (u6 + u7)));

        float bv = 3.4e38f; int bi = 0x7FFFFFFF;
        if (lane < 32) {
            unsigned int bits = cand[(size_t)p * 32 + lane];
            const int cb = (lane >> 2) * 128 + (lane & 3) * 32;
            while (bits) {
                int t = __builtin_ctz(bits);
                bits &= bits - 1;
                int c = cb + t;
                const float4* er4 = (const float4*)(E + (size_t)c * DIM);
                float acc = 0.f;
                for (int d4 = 0; d4 < DIM / 4; ++d4) {
                    float4 e4 = er4[d4];
                    float4 x4 = *(const float4*)&xsh[wave][d4 * 4];
                    acc = __builtin_fmaf(x4.x, e4.x, acc);
                    acc = __builtin_fmaf(x4.y, e4.y, acc);
                    acc = __builtin_fmaf(x4.z, e4.z, acc);
                    acc = __builtin_fmaf(x4.w, e4.w, acc);
                }
                float tt = A - 2.0f * acc;      // rounded subtract
                float dnp = tt + Cnp[c];        // rounded add (decisive grid)
                if (dnp < bv) { bv = dnp; bi = c; }
            }
        }
#pragma unroll
        for (int m = 1; m < 64; m <<= 1) {
            float ov = __shfl_xor(bv, m);
            int oi = __shfl_xor(bi, m);
            if (ov < bv || (ov == bv && oi < bi)) { bv = ov; bi = oi; }
        }
        if (active && lane == 0) final_idx[p] = bi;
    }
}

// ---------------- phase 4: gather, write quantized/indices, loss partials ----------------
__global__ void gather_kernel(const float* __restrict__ X, const float* __restrict__ E,
                              const int* __restrict__ final_idx,
                              float* __restrict__ out_q, float* __restrict__ out_idx,
                              float* __restrict__ ws_part) {
    const int tid = threadIdx.x;
    const int p = blockIdx.x * 16 + (tid >> 4);
    const int c = tid & 15;
    const int bi = final_idx[p];

    float ls = 0.f;
#pragma unroll
    for (int k = 0; k < 4; ++k) {
        int d4 = c + k * 16;
        float4 e4 = *(const float4*)(E + (size_t)bi * DIM + d4 * 4);
        float4 x4 = *(const float4*)(X + (size_t)p * DIM + d4 * 4);
        *(float4*)(out_q + (size_t)p * DIM + d4 * 4) = e4;
        float dx = e4.x - x4.x, dy = e4.y - x4.y, dz = e4.z - x4.z, dw = e4.w - x4.w;
        ls += dx * dx + dy * dy + dz * dz + dw * dw;
    }
    if (c == 0) out_idx[p] = (float)bi;

    __shared__ float red[256];
    red[tid] = ls;
    __syncthreads();
#pragma unroll
    for (int s = 128; s > 0; s >>= 1) {
        if (tid < s) red[tid] += red[tid + s];
        __syncthreads();
    }
    if (tid == 0) ws_part[blockIdx.x] = red[0];
}

// ---------------- phase 5: final loss reduce ----------------
__global__ void loss_kernel(const float* __restrict__ ws_part, float* __restrict__ out_loss) {
    const int tid = threadIdx.x;
    float s = 0.f;
    for (int i = tid; i < NPTS / 16; i += 256) s += ws_part[i];
    __shared__ float red[256];
    red[tid] = s;
    __syncthreads();
#pragma unroll
    for (int t = 128; t > 0; t >>= 1) {
        if (tid < t) red[tid] += red[tid + t];
        __syncthreads();
    }
    if (tid == 0)
        out_loss[0] = (1.f + 0.25f) * red[0] / (float)((size_t)NPTS * DIM);
}

extern "C" void kernel_launch(void* const* d_in, const int* in_sizes, int n_in,
                              void* d_out, int out_size, void* d_ws, size_t ws_size,
                              hipStream_t stream) {
    const float* X = (const float*)d_in[0];   // [32768, 256]
    const float* E = (const float*)d_in[1];   // [1024, 256]
    float* out = (float*)d_out;
    float* out_q = out;                                 // 8388608 floats
    float* out_loss = out + (size_t)NPTS * DIM;         // 1 float
    float* out_idx = out + (size_t)NPTS * DIM + 1;      // 32768 floats

    // staging inside out_q (rewritten by gather afterward):
    // Xb (16.8MB) + Eb (0.5MB) + cand (4.2MB) = 21.5MB < 33.5MB
    unsigned short* Xb = (unsigned short*)d_out;
    unsigned short* Eb = Xb + (size_t)NPTS * DIM;
    unsigned int* cand = (unsigned int*)(Eb + (size_t)KCODES * DIM);  // [NPTS][8][4] u32

    float* ws = (float*)d_ws;
    float* Cnp = ws;                                    // 1024
    float* ws_mm = Cnp + KCODES;                        // 32768*8*2 floats (2MB)
    int* final_idx = (int*)(ws_mm + (size_t)NPTS * NSPLIT * 2);  // 32768 ints
    int* counter = final_idx + NPTS;                    // 1 int (+63 pad)
    int* list = counter + 64;                           // 32768 ints
    float* ws_part = (float*)(list + NPTS);             // 2048 floats

    convert_kernel<<<(NPTS + KCODES) * DIM / 8 / 256, 256, 0, stream>>>(X, E, Xb, Eb);
    enormnp_kernel<<<KCODES / 256, 256, 0, stream>>>(E, Cnp, counter);
    dist_kernel<<<dim3(NPTS / BN, NSPLIT), 256, 0, stream>>>(Xb, Eb, Cnp, ws_mm, cand);
    resolve_kernel<<<NPTS / 256, 256, 0, stream>>>(ws_mm, cand, final_idx, list, counter);
    rescore_np_kernel<<<512, 256, 0, stream>>>(X, E, Cnp, cand, list, counter, final_idx);
    gather_kernel<<<NPTS / 16, 256, 0, stream>>>(X, E, final_idx, out_q, out_idx, ws_part);
    loss_kernel<<<1, 256, 0, stream>>>(ws_part, out_loss);
}